// Round 8
// baseline (370.039 us; speedup 1.0000x reference)
//
#include <hip/hip_runtime.h>
#include <math.h>

typedef unsigned short u16;
typedef __bf16 bf16x8 __attribute__((ext_vector_type(8)));
typedef float f32x4 __attribute__((ext_vector_type(4)));

#define LSEQ 2048
#define NB   4
#define NE   1024
#define NHEAD 8
#define ND1  2048
#define NHD  256
#define NM   8192          // LSEQ*NB
#define CRP  4104          // pitch of shifted-coeff rows (elements, mult of 8)
#define ZTP  272           // v-path transposed-epilogue LDS pitch (bank fix)

__device__ __forceinline__ u16 f2bf(float f) {
  unsigned u = __float_as_uint(f);
  u += 0x7FFFu + ((u >> 16) & 1u);       // RTNE
  return (u16)(u >> 16);
}
__device__ __forceinline__ float bf2f(u16 h) {
  return __uint_as_float(((unsigned)h) << 16);
}
__device__ __forceinline__ unsigned mulbf2(unsigned y2, unsigned u2) {
  float ylo = bf2f((u16)(y2 & 0xFFFF)), yhi = bf2f((u16)(y2 >> 16));
  float ulo = bf2f((u16)(u2 & 0xFFFF)), uhi = bf2f((u16)(u2 >> 16));
  return (unsigned)f2bf(ylo * ulo) | ((unsigned)f2bf(yhi * uhi) << 16);
}

// async global->LDS, 16B per lane; LDS dest is wave-uniform base + lane*16B
__device__ __forceinline__ void gl_lds16(const u16* g, u16* l) {
  __builtin_amdgcn_global_load_lds(
      (const __attribute__((address_space(1))) void*)g,
      (__attribute__((address_space(3))) void*)l, 16, 0, 0);
}

// ---------------- prep: 3x f32->bf16 weight convert + toeplitz cr8 ----------
__global__ __launch_bounds__(256) void prep_kernel(
    const float* __restrict__ uw, const float* __restrict__ vw,
    const float* __restrict__ ow, u16* __restrict__ uwb, u16* __restrict__ vwb,
    u16* __restrict__ owb, const float* __restrict__ pos,
    const float* __restrict__ zero, const float* __restrict__ neg,
    u16* __restrict__ cr8) {
  int bx = blockIdx.x;
  if (bx < 6144) {
    const float* s = bx < 2048 ? uw : (bx < 4096 ? vw : ow);
    u16* d = bx < 2048 ? uwb : (bx < 4096 ? vwb : owb);
    int i = (bx & 2047) * 256 + threadIdx.x;
    float4 v = ((const float4*)s)[i];
    ushort4 o;
    o.x = f2bf(v.x); o.y = f2bf(v.y); o.z = f2bf(v.z); o.w = f2bf(v.w);
    ((ushort4*)d)[i] = o;
  } else {
    int bb = bx - 6144;
    int h = bb >> 3, sh = bb & 7;
    u16* out = cr8 + (size_t)bb * CRP;
    for (int m = threadIdx.x; m < CRP; m += 256) {
      int mm = m + sh;
      float val = 0.f;
      if (mm <= 4094) {
        int t = 2047 - mm;                // t = i - j
        if (t == 0)      val = zero[h];
        else if (t > 0)  val = pos[h * (LSEQ - 1) + t - 1];
        else             val = neg[h * (LSEQ - 1) + (-t) - 1];
      }
      out[m] = f2bf(val);
    }
  }
}

// ---------------- RMSNorm: x = q / (||q||/sqrt(E) + 1e-8), bf16 out ----------
__global__ __launch_bounds__(256) void rmsnorm_kernel(const float* __restrict__ q,
                                                      u16* __restrict__ x) {
  int row = blockIdx.x;
  float4 v = ((const float4*)(q + (size_t)row * NE))[threadIdx.x];
  float ss = v.x * v.x + v.y * v.y + v.z * v.z + v.w * v.w;
  #pragma unroll
  for (int off = 32; off > 0; off >>= 1) ss += __shfl_down(ss, off, 64);
  __shared__ float wss[4];
  int wave = threadIdx.x >> 6, lane = threadIdx.x & 63;
  if (lane == 0) wss[wave] = ss;
  __syncthreads();
  float tot = wss[0] + wss[1] + wss[2] + wss[3];
  float scale = 1.f / (sqrtf(tot) * 0.03125f + 1e-8f);
  ushort4 o;
  o.x = f2bf(v.x * scale); o.y = f2bf(v.y * scale);
  o.z = f2bf(v.z * scale); o.w = f2bf(v.w * scale);
  ((ushort4*)(x + (size_t)row * NE))[threadIdx.x] = o;
}

// ================= 256x256 2-phase GEMM, 3-deep A ring (160 KiB LDS) =========
// 8 waves (2Mx4N), wave-tile 128x64, BK=64.
// LDS: A ring x3 (96 KiB) + B dbuf x2 (64 KiB) = 160 KiB.
// XOR chunk swizzle on stage-source + ds_read (0 conflicts, r2-verified).
// PH1: read A rt0-3 + B ct0-3; stage A(tt+2); barrier; lgkm; 32 MFMA; barrier.
// PH2: read A rt4-7; stage B(tt+2); vmcnt(8); barrier; lgkm; 32 MFMA; barrier.
// vmcnt ledger: entry in-flight A(tt+1)+B(tt+1)=8; +A(tt+2)+B(tt+2)=16;
// vmcnt(8) retires exactly tile tt+1. vmcnt(0) only at tt==nkt-2.
// XCD policy (r7 lesson): mode-0/gemm_out natural blockIdx already maps one
// weight panel per XCD (bx = lin%8 = XCD) -> NO swizzle; mode-1 swizzled so
// each XCD holds exactly one head's 4 MiB vT (-40 µs, r7-measured).

__device__ __forceinline__ bf16x8 ldsfrag(const u16* buf, int rr, int q) {
  return *(const bf16x8*)(buf + rr * 64 + ((q ^ (rr & 7)) * 8));
}

template <int MODE>
__device__ __forceinline__ void stage_Ah(const u16* A, const u16* Acr, int Ksz,
                                         int i0, int kt, int half, u16* dstbuf,
                                         int tid) {
  int wave = tid >> 6;
  #pragma unroll
  for (int it = 0; it < 2; ++it) {
    int vv = it * 512 + tid;               // 0..1023
    int r = vv >> 3, c8 = vv & 7, c8s = c8 ^ (r & 7);
    int row = i0 + half * 128 + r;
    const u16* src;
    if (MODE != 1) {
      src = A + (size_t)row * Ksz + kt * 64 + c8s * 8;
    } else {
      int p = 2047 - row + kt * 64;        // cr index of column 0
      int s = p & 7, qq = p - s;           // 8-aligned base in copy s
      src = Acr + (size_t)s * CRP + qq + c8s * 8;
    }
    gl_lds16(src, dstbuf + half * 8192 + (it * 512 + wave * 64) * 8);
  }
}

__device__ __forceinline__ void stage_Bh(const u16* B, int Ksz, int n0, int kt,
                                         int half, u16* dstbuf, int tid) {
  int wave = tid >> 6;
  #pragma unroll
  for (int it = 0; it < 2; ++it) {
    int vv = it * 512 + tid;
    int r = vv >> 3, c8 = vv & 7, c8s = c8 ^ (r & 7);
    gl_lds16(B + (size_t)(n0 + half * 128 + r) * Ksz + kt * 64 + c8s * 8,
             dstbuf + half * 8192 + (it * 512 + wave * 64) * 8);
  }
}

#define PHASE_MID()                                        \
  __builtin_amdgcn_s_barrier();                            \
  asm volatile("s_waitcnt lgkmcnt(0)" ::: "memory");       \
  __builtin_amdgcn_sched_barrier(0);                       \
  __builtin_amdgcn_s_setprio(1);

#define PHASE_END()                                        \
  __builtin_amdgcn_s_setprio(0);                           \
  __builtin_amdgcn_s_barrier();                            \
  __builtin_amdgcn_sched_barrier(0);

// MODE 0: z=0 -> C0 = u = silu(x@uw^T+ub); z=1 -> writes vT DIRECTLY
//         (transposed epilogue): vT[h=bx][b*256+d][j] = silu(x@vw^T+vb)
// MODE 1: A from cr8 (toeplitz); epilogue C0[ui] = u[ui] * acc (z=u*y)
template <int MODE>
__global__ __launch_bounds__(512, 2) void gemm256(
    const u16* __restrict__ A, const u16* __restrict__ Bw0,
    const u16* __restrict__ Bw1, const float* __restrict__ bias0,
    const float* __restrict__ bias1, u16* __restrict__ C0,
    u16* __restrict__ C1, int Msz, int Nsz, int Ksz) {
  extern __shared__ __align__(16) u16 lds[];
  u16* As = lds;             // 3 slots x 256x64 = 49152 u16 (96 KiB)
  u16* Ws = lds + 49152;     // 2 slots x 256x64 = 32768 u16 (64 KiB)

  unsigned bx, by, bz;
  if (MODE == 1) {
    // bijective XCD swizzle: one head's vT per XCD L2 (r7: -40 µs)
    unsigned gx = gridDim.x, gy = gridDim.y;
    unsigned nwg = gx * gy * gridDim.z;
    unsigned lin = blockIdx.x + gx * (blockIdx.y + gy * blockIdx.z);
    unsigned w = (lin & 7) * (nwg >> 3) + (lin >> 3);
    bx = w % gx; unsigned rest = w / gx;
    by = rest % gy; bz = rest / gy;
  } else {
    // natural order: bx = lin%8 = XCD -> one weight panel per XCD (r7 lesson)
    bx = blockIdx.x; by = blockIdx.y; bz = blockIdx.z;
  }

  const int tid = threadIdx.x;
  const int lane = tid & 63, wave = tid >> 6;
  const int wr = (wave >> 2) * 128, wc = (wave & 3) * 64;
  const int lr = lane & 15, lq = lane >> 4;
  const int i0 = by * 256, n0 = bx * 256;

  const u16* Bh;
  const u16* Acr = A;
  const float* bias = bias0;
  u16* Cp = C0;
  if (MODE == 0) {
    Bh = bz ? Bw1 : Bw0;
    bias = bz ? bias1 : bias0;
    Cp = bz ? C1 : C0;
  } else {
    Bh  = Bw0 + (size_t)bz * Nsz * Ksz;   // vT head base
    Acr = A + (size_t)bz * 8 * CRP;       // cr8 head base
  }
  const int nkt = Ksz >> 6;

  f32x4 acc[8][4];
  #pragma unroll
  for (int a = 0; a < 8; ++a)
    #pragma unroll
    for (int b = 0; b < 4; ++b) acc[a][b] = (f32x4){0.f, 0.f, 0.f, 0.f};

  // ---- prologue: A(0),B(0),A(1),B(1); wait tile0 (8 oldest) ----
  stage_Ah<MODE>(A, Acr, Ksz, i0, 0, 0, As, tid);
  stage_Ah<MODE>(A, Acr, Ksz, i0, 0, 1, As, tid);
  stage_Bh(Bh, Ksz, n0, 0, 0, Ws, tid);
  stage_Bh(Bh, Ksz, n0, 0, 1, Ws, tid);
  stage_Ah<MODE>(A, Acr, Ksz, i0, 1, 0, As + 16384, tid);
  stage_Ah<MODE>(A, Acr, Ksz, i0, 1, 1, As + 16384, tid);
  stage_Bh(Bh, Ksz, n0, 1, 0, Ws + 16384, tid);
  stage_Bh(Bh, Ksz, n0, 1, 1, Ws + 16384, tid);
  asm volatile("s_waitcnt vmcnt(8)" ::: "memory");   // A0,B0 landed
  __builtin_amdgcn_s_barrier();
  __builtin_amdgcn_sched_barrier(0);

  for (int tt = 0; tt < nkt; ++tt) {
    const u16* Ab = As + (tt % 3) * 16384;
    const u16* Wb = Ws + (tt & 1) * 16384;
    u16* An = As + ((tt + 2) % 3) * 16384;   // A of tile tt+2 (slot free)
    u16* Wn = Ws + (tt & 1) * 16384;         // B of tile tt+2 (B(tt) dead after PH1)

    bf16x8 a[4][2], b[4][2];

    // ---- PH1: read A rt0-3 (8) + B ct0-3 (8); stage A(tt+2) ----
    #pragma unroll
    for (int rt = 0; rt < 4; ++rt) {
      int ar = wr + rt * 16 + lr;
      a[rt][0] = ldsfrag(Ab, ar, lq);
      a[rt][1] = ldsfrag(Ab, ar, 4 + lq);
    }
    #pragma unroll
    for (int ct = 0; ct < 4; ++ct) {
      int br = wc + ct * 16 + lr;
      b[ct][0] = ldsfrag(Wb, br, lq);
      b[ct][1] = ldsfrag(Wb, br, 4 + lq);
    }
    if (tt + 2 < nkt) {
      stage_Ah<MODE>(A, Acr, Ksz, i0, tt + 2, 0, An, tid);
      stage_Ah<MODE>(A, Acr, Ksz, i0, tt + 2, 1, An, tid);
    }
    PHASE_MID();
    #pragma unroll
    for (int rt = 0; rt < 4; ++rt)
      #pragma unroll
      for (int ct = 0; ct < 4; ++ct) {
        acc[rt][ct] = __builtin_amdgcn_mfma_f32_16x16x32_bf16(a[rt][0], b[ct][0], acc[rt][ct], 0, 0, 0);
        acc[rt][ct] = __builtin_amdgcn_mfma_f32_16x16x32_bf16(a[rt][1], b[ct][1], acc[rt][ct], 0, 0, 0);
      }
    PHASE_END();

    // ---- PH2: read A rt4-7 (8); stage B(tt+2); counted vmcnt ----
    #pragma unroll
    for (int rt = 0; rt < 4; ++rt) {
      int ar = wr + (rt + 4) * 16 + lr;
      a[rt][0] = ldsfrag(Ab, ar, lq);
      a[rt][1] = ldsfrag(Ab, ar, 4 + lq);
    }
    if (tt + 2 < nkt) {
      stage_Bh(Bh, Ksz, n0, tt + 2, 0, Wn, tid);
      stage_Bh(Bh, Ksz, n0, tt + 2, 1, Wn, tid);
    }
    if (tt == nkt - 2) { asm volatile("s_waitcnt vmcnt(0)" ::: "memory"); }
    else               { asm volatile("s_waitcnt vmcnt(8)" ::: "memory"); }
    PHASE_MID();
    #pragma unroll
    for (int rt = 0; rt < 4; ++rt)
      #pragma unroll
      for (int ct = 0; ct < 4; ++ct) {
        acc[rt + 4][ct] = __builtin_amdgcn_mfma_f32_16x16x32_bf16(a[rt][0], b[ct][0], acc[rt + 4][ct], 0, 0, 0);
        acc[rt + 4][ct] = __builtin_amdgcn_mfma_f32_16x16x32_bf16(a[rt][1], b[ct][1], acc[rt + 4][ct], 0, 0, 0);
      }
    PHASE_END();
  }

  // ---- epilogue ----
  __syncthreads();
  if (MODE == 0 && bz == 1) {
    // v-path: silu -> TRANSPOSED LDS (pitch ZTP=272: col contributes to bank,
    // fixes r7's 16-way write conflict) -> direct vT write (head h = bx)
    u16* zt = lds;
    #pragma unroll
    for (int rt = 0; rt < 8; ++rt) {
      #pragma unroll
      for (int ct = 0; ct < 4; ++ct) {
        int col_l = wc + ct * 16 + lr;
        #pragma unroll
        for (int reg = 0; reg < 4; ++reg) {
          int row_l = wr + rt * 16 + lq * 4 + reg;
          float t = acc[rt][ct][reg] + bias[n0 + col_l];
          t = t / (1.f + __expf(-t));
          zt[col_l * ZTP + (row_l ^ (row_l >> 4) ^ ((col_l & 15) << 2))] = f2bf(t);
        }
      }
    }
    __syncthreads();
    int j0 = by * 64;
    #pragma unroll
    for (int it2 = 0; it2 < 32; ++it2) {
      int g = it2 * 512 + tid;
      int jq = g & 15, b2 = (g >> 4) & 3, d = g >> 6;
      int rl0 = 16 * jq + b2, sd = (d & 15) << 2;
      ushort4 o;
      o.x = zt[d * ZTP + ((rl0 + 0)  ^ ((rl0 + 0)  >> 4) ^ sd)];
      o.y = zt[d * ZTP + ((rl0 + 4)  ^ ((rl0 + 4)  >> 4) ^ sd)];
      o.z = zt[d * ZTP + ((rl0 + 8)  ^ ((rl0 + 8)  >> 4) ^ sd)];
      o.w = zt[d * ZTP + ((rl0 + 12) ^ ((rl0 + 12) >> 4) ^ sd)];
      *(ushort4*)&Cp[((size_t)bx * (NB * NHD) + b2 * NHD + d) * LSEQ + j0 + jq * 4] = o;
    }
    return;
  }
  // u-path / mode-1: linear-swizzled LDS -> coalesced 16B pass
  u16* zl = lds;                           // [256][256] bf16 = 128 KiB
  #pragma unroll
  for (int rt = 0; rt < 8; ++rt) {
    #pragma unroll
    for (int ct = 0; ct < 4; ++ct) {
      int col_l = wc + ct * 16 + lr;
      #pragma unroll
      for (int reg = 0; reg < 4; ++reg) {
        int row_l = wr + rt * 16 + lq * 4 + reg;
        float yv = acc[rt][ct][reg];
        if (MODE == 0) {
          float t = yv + bias[n0 + col_l];
          yv = t / (1.f + __expf(-t));     // silu
        }
        zl[row_l * 256 + (col_l ^ (((row_l >> 2) & 3) << 4))] = f2bf(yv);
      }
    }
  }
  __syncthreads();
  #pragma unroll
  for (int k = 0; k < 16; ++k) {
    int cc = k * 512 + tid;                // 0..8191 16B-chunks
    int row_l = cc >> 5, c8 = cc & 31;
    int colbase = c8 * 8;
    int swz = colbase ^ (((row_l >> 2) & 3) << 4);
    uint4 y4 = *(uint4*)&zl[row_l * 256 + swz];
    if (MODE == 0) {
      *(uint4*)&Cp[(size_t)(i0 + row_l) * Nsz + n0 + colbase] = y4;
    } else {
      size_t ui = ((size_t)(i0 + row_l) * NB + bx) * ND1 +
                  (size_t)bz * NHD + colbase;
      uint4 u4 = *(const uint4*)&Cp[ui];
      uint4 o;
      o.x = mulbf2(y4.x, u4.x); o.y = mulbf2(y4.y, u4.y);
      o.z = mulbf2(y4.z, u4.z); o.w = mulbf2(y4.w, u4.w);
      *(uint4*)&Cp[ui] = o;
    }
  }
}

// ---------------- 128x128 MFMA GEMM: out = z @ ow^T + ob + q  (f32) ----------
__global__ __launch_bounds__(256) void gemm_out(
    const u16* __restrict__ A, const u16* __restrict__ Bw,
    const float* __restrict__ bias, const float* __restrict__ resid,
    float* __restrict__ Cf, int Nsz, int Ksz) {
  __shared__ __align__(16) u16 As[128 * 64];
  __shared__ __align__(16) u16 Ws[128 * 64];

  const int tid = threadIdx.x;
  const int lane = tid & 63, wave = tid >> 6;
  const int wr = (wave >> 1) * 64, wc = (wave & 1) * 64;
  const int lr = lane & 15, lq = lane >> 4;
  const int i0 = blockIdx.y * 128, n0 = blockIdx.x * 128;

  f32x4 acc[4][4];
  #pragma unroll
  for (int a = 0; a < 4; ++a)
    #pragma unroll
    for (int b = 0; b < 4; ++b) acc[a][b] = (f32x4){0.f, 0.f, 0.f, 0.f};

  const int nkt = Ksz >> 6;
  for (int kt = 0; kt < nkt; ++kt) {
    #pragma unroll
    for (int it = 0; it < 4; ++it) {
      int vv = tid + 256 * it;
      int r = vv >> 3, c8 = vv & 7;
      int c8s = c8 ^ (r & 7);
      gl_lds16(A + (size_t)(i0 + r) * Ksz + kt * 64 + c8s * 8,
               &As[(size_t)(wave * 64 + it * 256) * 8]);
    }
    #pragma unroll
    for (int it = 0; it < 4; ++it) {
      int vv = tid + 256 * it;
      int r = vv >> 3, c8 = vv & 7;
      int c8s = c8 ^ (r & 7);
      gl_lds16(Bw + (size_t)(n0 + r) * Ksz + kt * 64 + c8s * 8,
               &Ws[(size_t)(wave * 64 + it * 256) * 8]);
    }
    __syncthreads();
    #pragma unroll
    for (int ks = 0; ks < 2; ++ks) {
      bf16x8 af[4], bfr[4];
      #pragma unroll
      for (int rt = 0; rt < 4; ++rt) {
        int ar = wr + rt * 16 + lr;
        int cq = (ks * 4 + lq) ^ (ar & 7);
        af[rt] = *(const bf16x8*)&As[ar * 64 + cq * 8];
      }
      #pragma unroll
      for (int ct = 0; ct < 4; ++ct) {
        int br = wc + ct * 16 + lr;
        int cq = (ks * 4 + lq) ^ (br & 7);
        bfr[ct] = *(const bf16x8*)&Ws[br * 64 + cq * 8];
      }
      #pragma unroll
      for (int rt = 0; rt < 4; ++rt)
        #pragma unroll
        for (int ct = 0; ct < 4; ++ct)
          acc[rt][ct] = __builtin_amdgcn_mfma_f32_16x16x32_bf16(
              af[rt], bfr[ct], acc[rt][ct], 0, 0, 0);
    }
    __syncthreads();
  }

  #pragma unroll
  for (int rt = 0; rt < 4; ++rt) {
    #pragma unroll
    for (int ct = 0; ct < 4; ++ct) {
      int col = n0 + wc + ct * 16 + lr;
      #pragma unroll
      for (int reg = 0; reg < 4; ++reg) {
        int row = i0 + wr + rt * 16 + lq * 4 + reg;
        size_t oi = (size_t)row * Nsz + col;
        Cf[oi] = acc[rt][ct][reg] + bias[col] + resid[oi];
      }
    }
  }
}

extern "C" void kernel_launch(void* const* d_in, const int* in_sizes, int n_in,
                              void* d_out, int out_size, void* d_ws, size_t ws_size,
                              hipStream_t stream) {
  const float* q    = (const float*)d_in[0];
  const float* uw   = (const float*)d_in[3];
  const float* ub   = (const float*)d_in[4];
  const float* vw   = (const float*)d_in[5];
  const float* vb   = (const float*)d_in[6];
  const float* ow   = (const float*)d_in[7];
  const float* ob   = (const float*)d_in[8];
  const float* pos  = (const float*)d_in[9];
  const float* zero = (const float*)d_in[10];
  const float* neg  = (const float*)d_in[11];
  float* out = (float*)d_out;

  char* ws = (char*)d_ws;
  u16* x   = (u16*)(ws + 0);            // 8192x1024 bf16 = 16 MiB
  u16* uwb = (u16*)(ws + 16777216);     // 4 MiB
  u16* vwb = (u16*)(ws + 20971520);     // 4 MiB
  u16* owb = (u16*)(ws + 25165824);     // 4 MiB
  u16* u   = (u16*)(ws + 29360128);     // 8192x2048 bf16 = 32 MiB (later z)
  u16* vT  = (u16*)(ws + 96468992);     // 32 MiB (v materialized only as vT)
  u16* cr8 = (u16*)(ws + 130023424);    // 8*8*4104*2 = 513 KiB

  // 160 KiB dynamic LDS (3-deep A ring + B dbuf)
  hipFuncSetAttribute((const void*)gemm256<0>,
                      hipFuncAttributeMaxDynamicSharedMemorySize, 163840);
  hipFuncSetAttribute((const void*)gemm256<1>,
                      hipFuncAttributeMaxDynamicSharedMemorySize, 163840);

  prep_kernel<<<6208, 256, 0, stream>>>(uw, vw, ow, uwb, vwb, owb,
                                        pos, zero, neg, cr8);
  rmsnorm_kernel<<<NM, 256, 0, stream>>>(q, x);

  // z=0: u = silu(x@uw^T+ub) -> u ; z=1: silu(x@vw^T+vb) -> vT (transposed)
  gemm256<0><<<dim3(8, 32, 2), 512, 163840, stream>>>(x, uwb, vwb, ub, vb, u, vT,
                                                      NM, ND1, NE);
  // per head: y = T_h @ vT_h^T ; z = u*y in place (in u buffer)
  gemm256<1><<<dim3(4, 8, 8), 512, 163840, stream>>>(cr8, vT, nullptr, nullptr,
                                                     nullptr, u, nullptr,
                                                     LSEQ, NB * NHD, LSEQ);
  // out = z @ ow^T + ob + q
  gemm_out<<<dim3(8, 64, 1), 256, 0, stream>>>(u, owb, ob, q, out, NE, ND1);
}

// Round 9
// 358.744 us; speedup vs baseline: 1.0315x; 1.0315x over previous
//
#include <hip/hip_runtime.h>
#include <math.h>

typedef unsigned short u16;
typedef __bf16 bf16x8 __attribute__((ext_vector_type(8)));
typedef float f32x4 __attribute__((ext_vector_type(4)));

#define LSEQ 2048
#define NB   4
#define NE   1024
#define NHEAD 8
#define ND1  2048
#define NHD  256
#define NM   8192          // LSEQ*NB
#define CRP  4104          // pitch of shifted-coeff rows (elements, mult of 8)
#define ZTP  272           // v-path transposed-epilogue LDS pitch

__device__ __forceinline__ u16 f2bf(float f) {
  unsigned u = __float_as_uint(f);
  u += 0x7FFFu + ((u >> 16) & 1u);       // RTNE
  return (u16)(u >> 16);
}
__device__ __forceinline__ float bf2f(u16 h) {
  return __uint_as_float(((unsigned)h) << 16);
}
__device__ __forceinline__ unsigned mulbf2(unsigned y2, unsigned u2) {
  float ylo = bf2f((u16)(y2 & 0xFFFF)), yhi = bf2f((u16)(y2 >> 16));
  float ulo = bf2f((u16)(u2 & 0xFFFF)), uhi = bf2f((u16)(u2 >> 16));
  return (unsigned)f2bf(ylo * ulo) | ((unsigned)f2bf(yhi * uhi) << 16);
}

// async global->LDS, 16B per lane; LDS dest is wave-uniform base + lane*16B
__device__ __forceinline__ void gl_lds16(const u16* g, u16* l) {
  __builtin_amdgcn_global_load_lds(
      (const __attribute__((address_space(1))) void*)g,
      (__attribute__((address_space(3))) void*)l, 16, 0, 0);
}

// -------- fused prep: rmsnorm (blocks 0..8191) + 3x cvt + cr8 build ---------
__global__ __launch_bounds__(256) void prep_kernel(
    const float* __restrict__ q, u16* __restrict__ x,
    const float* __restrict__ uw, const float* __restrict__ vw,
    const float* __restrict__ ow, u16* __restrict__ uwb, u16* __restrict__ vwb,
    u16* __restrict__ owb, const float* __restrict__ pos,
    const float* __restrict__ zero, const float* __restrict__ neg,
    u16* __restrict__ cr8) {
  int bx = blockIdx.x;
  if (bx < NM) {
    // RMSNorm: x = q / (||q||/sqrt(E) + 1e-8), bf16 out
    int row = bx;
    float4 v = ((const float4*)(q + (size_t)row * NE))[threadIdx.x];
    float ss = v.x * v.x + v.y * v.y + v.z * v.z + v.w * v.w;
    #pragma unroll
    for (int off = 32; off > 0; off >>= 1) ss += __shfl_down(ss, off, 64);
    __shared__ float wss[4];
    int wave = threadIdx.x >> 6, lane = threadIdx.x & 63;
    if (lane == 0) wss[wave] = ss;
    __syncthreads();
    float tot = wss[0] + wss[1] + wss[2] + wss[3];
    float scale = 1.f / (sqrtf(tot) * 0.03125f + 1e-8f);
    ushort4 o;
    o.x = f2bf(v.x * scale); o.y = f2bf(v.y * scale);
    o.z = f2bf(v.z * scale); o.w = f2bf(v.w * scale);
    ((ushort4*)(x + (size_t)row * NE))[threadIdx.x] = o;
  } else if (bx < NM + 6144) {
    int cb = bx - NM;
    const float* s = cb < 2048 ? uw : (cb < 4096 ? vw : ow);
    u16* d = cb < 2048 ? uwb : (cb < 4096 ? vwb : owb);
    int i = (cb & 2047) * 256 + threadIdx.x;
    float4 v = ((const float4*)s)[i];
    ushort4 o;
    o.x = f2bf(v.x); o.y = f2bf(v.y); o.z = f2bf(v.z); o.w = f2bf(v.w);
    ((ushort4*)d)[i] = o;
  } else {
    int bb = bx - NM - 6144;
    int h = bb >> 3, sh = bb & 7;
    u16* out = cr8 + (size_t)bb * CRP;
    for (int m = threadIdx.x; m < CRP; m += 256) {
      int mm = m + sh;
      float val = 0.f;
      if (mm <= 4094) {
        int t = 2047 - mm;                // t = i - j
        if (t == 0)      val = zero[h];
        else if (t > 0)  val = pos[h * (LSEQ - 1) + t - 1];
        else             val = neg[h * (LSEQ - 1) + (-t) - 1];
      }
      out[m] = f2bf(val);
    }
  }
}

// ================= 256x256 2-phase GEMM, 3-deep A ring (160 KiB LDS) =========
// 8 waves (2Mx4N), wave-tile 128x64, BK=64.
// LDS: A ring x3 (96 KiB) + B dbuf x2 (64 KiB) = 160 KiB.
// XOR chunk swizzle on stage-source + ds_read (0 conflicts, r2-verified).
// PH1: read A rt0-3 + B ct0-3; stage A(tt+2); barrier; lgkm; 32 MFMA; barrier.
// PH2: read A rt4-7; stage B(tt+2); vmcnt(8); barrier; lgkm; 32 MFMA; barrier.
// vmcnt ledger: entry in-flight A(tt+1)+B(tt+1)=8; +A(tt+2)+B(tt+2)=16;
// vmcnt(8) retires exactly tile tt+1. vmcnt(0) only at tt==nkt-2.
// XCD policy (r7/r8 A/B): mode-0 NATURAL (swizzle cost +41 µs, r7);
// mode-1 swizzled (one head's vT per XCD, r7: -40 µs);
// gemm_out swizzled (r8 revert cost +50 µs).

__device__ __forceinline__ bf16x8 ldsfrag(const u16* buf, int rr, int q) {
  return *(const bf16x8*)(buf + rr * 64 + ((q ^ (rr & 7)) * 8));
}

template <int MODE>
__device__ __forceinline__ void stage_Ah(const u16* A, const u16* Acr, int Ksz,
                                         int i0, int kt, int half, u16* dstbuf,
                                         int tid) {
  int wave = tid >> 6;
  #pragma unroll
  for (int it = 0; it < 2; ++it) {
    int vv = it * 512 + tid;               // 0..1023
    int r = vv >> 3, c8 = vv & 7, c8s = c8 ^ (r & 7);
    int row = i0 + half * 128 + r;
    const u16* src;
    if (MODE != 1) {
      src = A + (size_t)row * Ksz + kt * 64 + c8s * 8;
    } else {
      int p = 2047 - row + kt * 64;        // cr index of column 0
      int s = p & 7, qq = p - s;           // 8-aligned base in copy s
      src = Acr + (size_t)s * CRP + qq + c8s * 8;
    }
    gl_lds16(src, dstbuf + half * 8192 + (it * 512 + wave * 64) * 8);
  }
}

__device__ __forceinline__ void stage_Bh(const u16* B, int Ksz, int n0, int kt,
                                         int half, u16* dstbuf, int tid) {
  int wave = tid >> 6;
  #pragma unroll
  for (int it = 0; it < 2; ++it) {
    int vv = it * 512 + tid;
    int r = vv >> 3, c8 = vv & 7, c8s = c8 ^ (r & 7);
    gl_lds16(B + (size_t)(n0 + half * 128 + r) * Ksz + kt * 64 + c8s * 8,
             dstbuf + half * 8192 + (it * 512 + wave * 64) * 8);
  }
}

#define PHASE_MID()                                        \
  __builtin_amdgcn_s_barrier();                            \
  asm volatile("s_waitcnt lgkmcnt(0)" ::: "memory");       \
  __builtin_amdgcn_sched_barrier(0);                       \
  __builtin_amdgcn_s_setprio(1);

#define PHASE_END()                                        \
  __builtin_amdgcn_s_setprio(0);                           \
  __builtin_amdgcn_s_barrier();                            \
  __builtin_amdgcn_sched_barrier(0);

// MODE 0: z=0 -> C0 = u = silu(x@uw^T+ub); z=1 -> writes vT DIRECTLY
//         (transposed epilogue): vT[h=bx][b*256+d][j] = silu(x@vw^T+vb)
// MODE 1: A from cr8 (toeplitz); epilogue C0[ui] = u[ui] * acc (z=u*y)
template <int MODE>
__global__ __launch_bounds__(512, 2) void gemm256(
    const u16* __restrict__ A, const u16* __restrict__ Bw0,
    const u16* __restrict__ Bw1, const float* __restrict__ bias0,
    const float* __restrict__ bias1, u16* __restrict__ C0,
    u16* __restrict__ C1, int Msz, int Nsz, int Ksz) {
  extern __shared__ __align__(16) u16 lds[];
  u16* As = lds;             // 3 slots x 256x64 = 49152 u16 (96 KiB)
  u16* Ws = lds + 49152;     // 2 slots x 256x64 = 32768 u16 (64 KiB)

  unsigned bx, by, bz;
  if (MODE == 1) {
    // bijective XCD swizzle: one head's vT per XCD L2 (r7: -40 µs)
    unsigned gx = gridDim.x, gy = gridDim.y;
    unsigned nwg = gx * gy * gridDim.z;
    unsigned lin = blockIdx.x + gx * (blockIdx.y + gy * blockIdx.z);
    unsigned w = (lin & 7) * (nwg >> 3) + (lin >> 3);
    bx = w % gx; unsigned rest = w / gx;
    by = rest % gy; bz = rest / gy;
  } else {
    // natural order: hot 1 MiB weight panel per XCD (r7/r8 A/B)
    bx = blockIdx.x; by = blockIdx.y; bz = blockIdx.z;
  }

  const int tid = threadIdx.x;
  const int lane = tid & 63, wave = tid >> 6;
  const int wr = (wave >> 2) * 128, wc = (wave & 3) * 64;
  const int lr = lane & 15, lq = lane >> 4;
  const int i0 = by * 256, n0 = bx * 256;

  const u16* Bh;
  const u16* Acr = A;
  const float* bias = bias0;
  u16* Cp = C0;
  if (MODE == 0) {
    Bh = bz ? Bw1 : Bw0;
    bias = bz ? bias1 : bias0;
    Cp = bz ? C1 : C0;
  } else {
    Bh  = Bw0 + (size_t)bz * Nsz * Ksz;   // vT head base
    Acr = A + (size_t)bz * 8 * CRP;       // cr8 head base
  }
  const int nkt = Ksz >> 6;

  f32x4 acc[8][4];
  #pragma unroll
  for (int a = 0; a < 8; ++a)
    #pragma unroll
    for (int b = 0; b < 4; ++b) acc[a][b] = (f32x4){0.f, 0.f, 0.f, 0.f};

  // ---- prologue: A(0),B(0),A(1),B(1); wait tile0 (8 oldest) ----
  stage_Ah<MODE>(A, Acr, Ksz, i0, 0, 0, As, tid);
  stage_Ah<MODE>(A, Acr, Ksz, i0, 0, 1, As, tid);
  stage_Bh(Bh, Ksz, n0, 0, 0, Ws, tid);
  stage_Bh(Bh, Ksz, n0, 0, 1, Ws, tid);
  stage_Ah<MODE>(A, Acr, Ksz, i0, 1, 0, As + 16384, tid);
  stage_Ah<MODE>(A, Acr, Ksz, i0, 1, 1, As + 16384, tid);
  stage_Bh(Bh, Ksz, n0, 1, 0, Ws + 16384, tid);
  stage_Bh(Bh, Ksz, n0, 1, 1, Ws + 16384, tid);
  asm volatile("s_waitcnt vmcnt(8)" ::: "memory");   // A0,B0 landed
  __builtin_amdgcn_s_barrier();
  __builtin_amdgcn_sched_barrier(0);

  for (int tt = 0; tt < nkt; ++tt) {
    const u16* Ab = As + (tt % 3) * 16384;
    const u16* Wb = Ws + (tt & 1) * 16384;
    u16* An = As + ((tt + 2) % 3) * 16384;   // A of tile tt+2 (slot free)
    u16* Wn = Ws + (tt & 1) * 16384;         // B of tile tt+2 (B(tt) dead after PH1)

    bf16x8 a[4][2], b[4][2];

    // ---- PH1: read A rt0-3 (8) + B ct0-3 (8); stage A(tt+2) ----
    #pragma unroll
    for (int rt = 0; rt < 4; ++rt) {
      int ar = wr + rt * 16 + lr;
      a[rt][0] = ldsfrag(Ab, ar, lq);
      a[rt][1] = ldsfrag(Ab, ar, 4 + lq);
    }
    #pragma unroll
    for (int ct = 0; ct < 4; ++ct) {
      int br = wc + ct * 16 + lr;
      b[ct][0] = ldsfrag(Wb, br, lq);
      b[ct][1] = ldsfrag(Wb, br, 4 + lq);
    }
    if (tt + 2 < nkt) {
      stage_Ah<MODE>(A, Acr, Ksz, i0, tt + 2, 0, An, tid);
      stage_Ah<MODE>(A, Acr, Ksz, i0, tt + 2, 1, An, tid);
    }
    PHASE_MID();
    #pragma unroll
    for (int rt = 0; rt < 4; ++rt)
      #pragma unroll
      for (int ct = 0; ct < 4; ++ct) {
        acc[rt][ct] = __builtin_amdgcn_mfma_f32_16x16x32_bf16(a[rt][0], b[ct][0], acc[rt][ct], 0, 0, 0);
        acc[rt][ct] = __builtin_amdgcn_mfma_f32_16x16x32_bf16(a[rt][1], b[ct][1], acc[rt][ct], 0, 0, 0);
      }
    PHASE_END();

    // ---- PH2: read A rt4-7 (8); stage B(tt+2); counted vmcnt ----
    #pragma unroll
    for (int rt = 0; rt < 4; ++rt) {
      int ar = wr + (rt + 4) * 16 + lr;
      a[rt][0] = ldsfrag(Ab, ar, lq);
      a[rt][1] = ldsfrag(Ab, ar, 4 + lq);
    }
    if (tt + 2 < nkt) {
      stage_Bh(Bh, Ksz, n0, tt + 2, 0, Wn, tid);
      stage_Bh(Bh, Ksz, n0, tt + 2, 1, Wn, tid);
    }
    if (tt == nkt - 2) { asm volatile("s_waitcnt vmcnt(0)" ::: "memory"); }
    else               { asm volatile("s_waitcnt vmcnt(8)" ::: "memory"); }
    PHASE_MID();
    #pragma unroll
    for (int rt = 0; rt < 4; ++rt)
      #pragma unroll
      for (int ct = 0; ct < 4; ++ct) {
        acc[rt + 4][ct] = __builtin_amdgcn_mfma_f32_16x16x32_bf16(a[rt][0], b[ct][0], acc[rt + 4][ct], 0, 0, 0);
        acc[rt + 4][ct] = __builtin_amdgcn_mfma_f32_16x16x32_bf16(a[rt][1], b[ct][1], acc[rt + 4][ct], 0, 0, 0);
      }
    PHASE_END();
  }

  // ---- epilogue ----
  __syncthreads();
  if (MODE == 0 && bz == 1) {
    // v-path: silu -> transposed LDS -> direct vT write (head h = bx)
    u16* zt = lds;
    #pragma unroll
    for (int rt = 0; rt < 8; ++rt) {
      #pragma unroll
      for (int ct = 0; ct < 4; ++ct) {
        int col_l = wc + ct * 16 + lr;
        #pragma unroll
        for (int reg = 0; reg < 4; ++reg) {
          int row_l = wr + rt * 16 + lq * 4 + reg;
          float t = acc[rt][ct][reg] + bias[n0 + col_l];
          t = t / (1.f + __expf(-t));
          zt[col_l * ZTP + (row_l ^ (row_l >> 4) ^ ((col_l & 15) << 2))] = f2bf(t);
        }
      }
    }
    __syncthreads();
    int j0 = by * 64;
    #pragma unroll
    for (int it2 = 0; it2 < 32; ++it2) {
      int g = it2 * 512 + tid;
      int jq = g & 15, b2 = (g >> 4) & 3, d = g >> 6;
      int rl0 = 16 * jq + b2, sd = (d & 15) << 2;
      ushort4 o;
      o.x = zt[d * ZTP + ((rl0 + 0)  ^ ((rl0 + 0)  >> 4) ^ sd)];
      o.y = zt[d * ZTP + ((rl0 + 4)  ^ ((rl0 + 4)  >> 4) ^ sd)];
      o.z = zt[d * ZTP + ((rl0 + 8)  ^ ((rl0 + 8)  >> 4) ^ sd)];
      o.w = zt[d * ZTP + ((rl0 + 12) ^ ((rl0 + 12) >> 4) ^ sd)];
      *(ushort4*)&Cp[((size_t)bx * (NB * NHD) + b2 * NHD + d) * LSEQ + j0 + jq * 4] = o;
    }
    return;
  }
  // u-path / mode-1: linear-swizzled LDS -> coalesced 16B pass
  u16* zl = lds;                           // [256][256] bf16 = 128 KiB
  #pragma unroll
  for (int rt = 0; rt < 8; ++rt) {
    #pragma unroll
    for (int ct = 0; ct < 4; ++ct) {
      int col_l = wc + ct * 16 + lr;
      #pragma unroll
      for (int reg = 0; reg < 4; ++reg) {
        int row_l = wr + rt * 16 + lq * 4 + reg;
        float yv = acc[rt][ct][reg];
        if (MODE == 0) {
          float t = yv + bias[n0 + col_l];
          yv = t / (1.f + __expf(-t));     // silu
        }
        zl[row_l * 256 + (col_l ^ (((row_l >> 2) & 3) << 4))] = f2bf(yv);
      }
    }
  }
  __syncthreads();
  #pragma unroll
  for (int k = 0; k < 16; ++k) {
    int cc = k * 512 + tid;                // 0..8191 16B-chunks
    int row_l = cc >> 5, c8 = cc & 31;
    int colbase = c8 * 8;
    int swz = colbase ^ (((row_l >> 2) & 3) << 4);
    uint4 y4 = *(uint4*)&zl[row_l * 256 + swz];
    if (MODE == 0) {
      *(uint4*)&Cp[(size_t)(i0 + row_l) * Nsz + n0 + colbase] = y4;
    } else {
      size_t ui = ((size_t)(i0 + row_l) * NB + bx) * ND1 +
                  (size_t)bz * NHD + colbase;
      uint4 u4 = *(const uint4*)&Cp[ui];
      uint4 o;
      o.x = mulbf2(y4.x, u4.x); o.y = mulbf2(y4.y, u4.y);
      o.z = mulbf2(y4.z, u4.z); o.w = mulbf2(y4.w, u4.w);
      *(uint4*)&Cp[ui] = o;
    }
  }
}

// ---------------- 128x128 MFMA GEMM: out = z @ ow^T + ob + q  (f32) ----------
__global__ __launch_bounds__(256) void gemm_out(
    const u16* __restrict__ A, const u16* __restrict__ Bw,
    const float* __restrict__ bias, const float* __restrict__ resid,
    float* __restrict__ Cf, int Nsz, int Ksz) {
  __shared__ __align__(16) u16 As[128 * 64];
  __shared__ __align__(16) u16 Ws[128 * 64];

  // bijective XCD swizzle: 8 z-row-panels per XCD L2 (r7<->r8 A/B: -50 µs)
  unsigned gx = gridDim.x, gy = gridDim.y;
  unsigned nwg = gx * gy;
  unsigned lin = blockIdx.x + gx * blockIdx.y;
  unsigned w = (lin & 7) * (nwg >> 3) + (lin >> 3);
  unsigned bx = w % gx, by = w / gx;

  const int tid = threadIdx.x;
  const int lane = tid & 63, wave = tid >> 6;
  const int wr = (wave >> 1) * 64, wc = (wave & 1) * 64;
  const int lr = lane & 15, lq = lane >> 4;
  const int i0 = by * 128, n0 = bx * 128;

  f32x4 acc[4][4];
  #pragma unroll
  for (int a = 0; a < 4; ++a)
    #pragma unroll
    for (int b = 0; b < 4; ++b) acc[a][b] = (f32x4){0.f, 0.f, 0.f, 0.f};

  const int nkt = Ksz >> 6;
  for (int kt = 0; kt < nkt; ++kt) {
    #pragma unroll
    for (int it = 0; it < 4; ++it) {
      int vv = tid + 256 * it;
      int r = vv >> 3, c8 = vv & 7;
      int c8s = c8 ^ (r & 7);
      gl_lds16(A + (size_t)(i0 + r) * Ksz + kt * 64 + c8s * 8,
               &As[(size_t)(wave * 64 + it * 256) * 8]);
    }
    #pragma unroll
    for (int it = 0; it < 4; ++it) {
      int vv = tid + 256 * it;
      int r = vv >> 3, c8 = vv & 7;
      int c8s = c8 ^ (r & 7);
      gl_lds16(Bw + (size_t)(n0 + r) * Ksz + kt * 64 + c8s * 8,
               &Ws[(size_t)(wave * 64 + it * 256) * 8]);
    }
    __syncthreads();
    #pragma unroll
    for (int ks = 0; ks < 2; ++ks) {
      bf16x8 af[4], bfr[4];
      #pragma unroll
      for (int rt = 0; rt < 4; ++rt) {
        int ar = wr + rt * 16 + lr;
        int cq = (ks * 4 + lq) ^ (ar & 7);
        af[rt] = *(const bf16x8*)&As[ar * 64 + cq * 8];
      }
      #pragma unroll
      for (int ct = 0; ct < 4; ++ct) {
        int br = wc + ct * 16 + lr;
        int cq = (ks * 4 + lq) ^ (br & 7);
        bfr[ct] = *(const bf16x8*)&Ws[br * 64 + cq * 8];
      }
      #pragma unroll
      for (int rt = 0; rt < 4; ++rt)
        #pragma unroll
        for (int ct = 0; ct < 4; ++ct)
          acc[rt][ct] = __builtin_amdgcn_mfma_f32_16x16x32_bf16(
              af[rt], bfr[ct], acc[rt][ct], 0, 0, 0);
    }
    __syncthreads();
  }

  #pragma unroll
  for (int rt = 0; rt < 4; ++rt) {
    #pragma unroll
    for (int ct = 0; ct < 4; ++ct) {
      int col = n0 + wc + ct * 16 + lr;
      #pragma unroll
      for (int reg = 0; reg < 4; ++reg) {
        int row = i0 + wr + rt * 16 + lq * 4 + reg;
        size_t oi = (size_t)row * Nsz + col;
        Cf[oi] = acc[rt][ct][reg] + bias[col] + resid[oi];
      }
    }
  }
}

extern "C" void kernel_launch(void* const* d_in, const int* in_sizes, int n_in,
                              void* d_out, int out_size, void* d_ws, size_t ws_size,
                              hipStream_t stream) {
  const float* q    = (const float*)d_in[0];
  const float* uw   = (const float*)d_in[3];
  const float* ub   = (const float*)d_in[4];
  const float* vw   = (const float*)d_in[5];
  const float* vb   = (const float*)d_in[6];
  const float* ow   = (const float*)d_in[7];
  const float* ob   = (const float*)d_in[8];
  const float* pos  = (const float*)d_in[9];
  const float* zero = (const float*)d_in[10];
  const float* neg  = (const float*)d_in[11];
  float* out = (float*)d_out;

  char* ws = (char*)d_ws;
  u16* x   = (u16*)(ws + 0);            // 8192x1024 bf16 = 16 MiB
  u16* uwb = (u16*)(ws + 16777216);     // 4 MiB
  u16* vwb = (u16*)(ws + 20971520);     // 4 MiB
  u16* owb = (u16*)(ws + 25165824);     // 4 MiB
  u16* u   = (u16*)(ws + 29360128);     // 8192x2048 bf16 = 32 MiB (later z)
  u16* vT  = (u16*)(ws + 96468992);     // 32 MiB (v materialized only as vT)
  u16* cr8 = (u16*)(ws + 130023424);    // 8*8*4104*2 = 513 KiB

  // 160 KiB dynamic LDS (3-deep A ring + B dbuf)
  hipFuncSetAttribute((const void*)gemm256<0>,
                      hipFuncAttributeMaxDynamicSharedMemorySize, 163840);
  hipFuncSetAttribute((const void*)gemm256<1>,
                      hipFuncAttributeMaxDynamicSharedMemorySize, 163840);

  // fused: rmsnorm (8192) + weight cvt (6144) + cr8 (64) in one launch
  prep_kernel<<<NM + 6208, 256, 0, stream>>>(q, x, uw, vw, ow, uwb, vwb, owb,
                                             pos, zero, neg, cr8);

  // z=0: u = silu(x@uw^T+ub) -> u ; z=1: silu(x@vw^T+vb) -> vT (transposed)
  gemm256<0><<<dim3(8, 32, 2), 512, 163840, stream>>>(x, uwb, vwb, ub, vb, u, vT,
                                                      NM, ND1, NE);
  // per head: y = T_h @ vT_h^T ; z = u*y in place (in u buffer)
  gemm256<1><<<dim3(4, 8, 8), 512, 163840, stream>>>(cr8, vT, nullptr, nullptr,
                                                     nullptr, u, nullptr,
                                                     LSEQ, NB * NHD, LSEQ);
  // out = z @ ow^T + ob + q
  gemm_out<<<dim3(8, 64, 1), 256, 0, stream>>>(u, owb, ob, q, out, NE, ND1);
}